// Round 8
// baseline (98.561 us; speedup 1.0000x reference)
//
#include <hip/hip_runtime.h>

// MFMA-batched overlapped-chunk HMM forward filter.
// R13: non-temporal stores. R12 (2x occupancy, 1.33x work) left the kernel
// invariant at ~18us == 66MB / 3.6 TB/s -> write-path-bound, matching the
// write-allocate theory: 64B-segment stores into 128B lines, two stores to
// the same line separated by a full FSTEP chain -> first store allocates ->
// L2 fetches 128B from HBM (~66MB hidden FETCH; (66+66)MB / 6TB/s ~= 22us
// ~= observed). R11's full-line LDS flush would have fixed it but paid more
// in occupancy+LDS serialization. Fix here: __builtin_nontemporal_store
// (nt bit -> no-allocate streaming write), zero structural change vs R12.
// Predicted: kernel 18.2 -> ~12us, total 89 -> ~83; absmax unchanged.
#define CHUNK_L 16
#define WARMUP_W 16

typedef _Float16 h16;
typedef _Float16 h16x4 __attribute__((ext_vector_type(4)));
typedef float f32x4 __attribute__((ext_vector_type(4)));

static __device__ __forceinline__ f32x4 mfma16(h16x4 a, h16x4 b, f32x4 c) {
#if __has_builtin(__builtin_amdgcn_mfma_f32_16x16x16f16)
    return __builtin_amdgcn_mfma_f32_16x16x16f16(a, b, c, 0, 0, 0);
#else
    f32x4 d;
    asm volatile("v_mfma_f32_16x16x16_f16 %0, %1, %2, %3\n\ts_nop 7\n\ts_nop 7"
                 : "=v"(d) : "v"(a), "v"(b), "v"(c));
    return d;
#endif
}

__global__ __launch_bounds__(256, 4) void hmm_filter_kernel(
    const float* __restrict__ y,
    const float* __restrict__ logits,
    const float* __restrict__ mu,
    const float* __restrict__ log_sigma,
    float* __restrict__ out,
    int T, int nchunks)
{
    __shared__ float Plds[256];
    __shared__ float Ba[256];
    __shared__ float Bb[256];

    const int tid = (int)threadIdx.x;
    const int j   = tid & 15;     // column (preamble)
    const int gr  = tid >> 4;     // row (preamble)

    // ---- P = softmax(logits, axis=-1) ----
    float l = logits[tid];
    float m = l;
    #pragma unroll
    for (int s = 1; s < 16; s <<= 1) m = fmaxf(m, __shfl_xor(m, s, 16));
    float e = __expf(l - m);
    float rs = e;
    #pragma unroll
    for (int s = 1; s < 16; s <<= 1) rs += __shfl_xor(rs, s, 16);
    float Pv = e / rs;
    Plds[tid] = Pv;
    Ba[tid]   = Pv;
    __syncthreads();

    // ---- stationary pi: P^(2^10) via renormalized squaring (cold) ----
    float* cur = Ba;
    float* nxt = Bb;
    for (int itq = 0; itq < 10; ++itq) {
        float acc = 0.f;
        #pragma unroll
        for (int k = 0; k < 16; ++k)
            acc += cur[gr * 16 + k] * cur[k * 16 + j];
        float rsum = acc;
        #pragma unroll
        for (int s = 1; s < 16; s <<= 1) rsum += __shfl_xor(rsum, s, 16);
        nxt[tid] = acc / rsum;
        __syncthreads();
        float* tmp = cur; cur = nxt; nxt = tmp;
    }
    // no barriers below this point (early return is safe)

    // ---- lane / wave geometry ----
    const int lane = tid & 63;
    const int col  = lane & 15;          // chunk column  (n)
    const int i0   = (lane >> 4) << 2;   // first of this lane's 4 states
    const int wv   = ((int)blockIdx.x << 2) + (tid >> 6);
    const int cbase = wv << 4;

    // A = P^T fragments, hi/lo f16 split.  A[m][k]: m=lane%16, k=i0+ee.
    // A[m][k] = P[k][m] = Plds[(i0+ee)*16 + col].
    h16x4 Ahi, Alo;
    #pragma unroll
    for (int ee = 0; ee < 4; ++ee) {
        float a = Plds[(i0 + ee) * 16 + col];
        h16 hi = (h16)a;
        Ahi[ee] = hi;
        Alo[ee] = (h16)(a - (float)hi);
    }

    // initial p~ = pi  (B[k][n]: k=i0+ee, same for every chunk column)
    h16x4 bhi, blo;
    #pragma unroll
    for (int ee = 0; ee < 4; ++ee) {
        float pv = cur[i0 + ee];
        h16 hi = (h16)pv;
        bhi[ee] = hi;
        blo[ee] = (h16)(pv - (float)hi);
    }

    // emission constants for this lane's 4 states
    float isv[4], nmv[4], lcv[4];
    #pragma unroll
    for (int ee = 0; ee < 4; ++ee) {
        int st = i0 + ee;
        float is = __expf(-log_sigma[st]);
        isv[ee] = is;
        nmv[ee] = -mu[st] * is;
        lcv[ee] = __log2f(0.3989422804014327f * is);
    }
    const float K2 = -0.7213475204444817f;   // -0.5*log2(e)

    if (cbase >= nchunks) return;

    const int chunk = cbase + col;
    const bool live = chunk < nchunks;       // ghost chunks: no stores
    const bool isC0 = (chunk == 0);          // warm with g==1 (pi stationary)
    const int Tm4 = T - 4;
    const int TN  = T << 4;

    int tb = chunk * CHUNK_L - WARMUP_W;     // t of current y 4-block

    auto yld = [&](int t) -> float4 {
        int tc = t < 0 ? 0 : (t > Tm4 ? Tm4 : t);
        return *(const float4*)(y + tc);
    };

    float4 c4 = yld(tb);
    float4 n1 = yld(tb + 4);

    float r1 = 1.0f;   // rcp(rowsum of previous step) = 1/c_{t-1}

// One filter step. Chain: 3 MFMA -> *eg -> f16 split. rowsum/rcp, outputs
// hang off the chain. alpha = r1 (1-step lag) keeps carried scale = f_t.
// Stores are NON-TEMPORAL (nt): outputs never re-read -> no L2 allocate.
#define FSTEP(YT, WARM, DOST, UTP, UNP, FDST)  do {                       \
    f32x4 D = {0.f, 0.f, 0.f, 0.f};                                       \
    D = mfma16(Ahi, bhi, D);                                              \
    D = mfma16(Alo, bhi, D);                                              \
    D = mfma16(Ahi, blo, D);                                              \
    f32x4 eg;                                                             \
    _Pragma("unroll")                                                     \
    for (int ee = 0; ee < 4; ++ee) {                                      \
        float z  = fmaf((YT), isv[ee], nmv[ee]);                          \
        float gg = __builtin_amdgcn_exp2f(fmaf(z * z, K2, lcv[ee]));      \
        if (WARM) gg = isC0 ? 1.0f : gg;                                  \
        eg[ee] = gg * r1;                                                 \
    }                                                                     \
    f32x4 pg = D * eg;                                                    \
    float sv = (pg.x + pg.y) + (pg.z + pg.w);                             \
    sv += __shfl_xor(sv, 16);                                             \
    sv += __shfl_xor(sv, 32);                                             \
    float rv = __builtin_amdgcn_rcpf(sv);                                 \
    if ((DOST) && live) {                                                 \
        f32x4 ut = D * r1;                                                \
        f32x4 un = pg * rv;                                               \
        __builtin_nontemporal_store(ut, (f32x4*)(UTP));                   \
        __builtin_nontemporal_store(un, (f32x4*)(UNP));                   \
    }                                                                     \
    if (DOST) { FDST = sv; }                                              \
    _Pragma("unroll")                                                     \
    for (int ee = 0; ee < 4; ++ee) {                                      \
        h16 hh = (h16)pg[ee];                                             \
        bhi[ee] = hh;                                                     \
        blo[ee] = (h16)(pg[ee] - (float)hh);                              \
    }                                                                     \
    r1 = rv;                                                              \
} while (0)

    // ---- warm-up: 16 steps, no stores ----
    float fdummy;
    #pragma unroll 1
    for (int b = 0; b < WARMUP_W / 4; ++b) {
        float4 nn = yld(tb + 8);
        FSTEP(c4.x, true, false, out, out, fdummy);
        FSTEP(c4.y, true, false, out, out, fdummy);
        FSTEP(c4.z, true, false, out, out, fdummy);
        FSTEP(c4.w, true, false, out, out, fdummy);
        c4 = n1; n1 = nn; tb += 4;
    }
    (void)fdummy;

    // ---- main: CHUNK_L steps with stores ----
    float* pU = out + ((chunk * CHUNK_L) << 4) + i0;   // ut  [t][state]
    float* pN = pU + TN;                               // u_norm
    float* pF = out + 2 * TN + chunk * CHUNK_L;        // ft (lanes<16)
    f32x4 f4;

    #pragma unroll 1
    for (int b = 0; b < CHUNK_L / 4; ++b) {
        float4 nn = yld(tb + 8);
        FSTEP(c4.x, false, true, pU,      pN,      f4.x);
        FSTEP(c4.y, false, true, pU + 16, pN + 16, f4.y);
        FSTEP(c4.z, false, true, pU + 32, pN + 32, f4.z);
        FSTEP(c4.w, false, true, pU + 48, pN + 48, f4.w);
        if (lane < 16 && live)
            __builtin_nontemporal_store(f4, (f32x4*)(pF));
        pU += 64; pN += 64; pF += 4;
        c4 = n1; n1 = nn; tb += 4;
    }
#undef FSTEP
}

extern "C" void kernel_launch(void* const* d_in, const int* in_sizes, int n_in,
                              void* d_out, int out_size, void* d_ws, size_t ws_size,
                              hipStream_t stream) {
    const float* y      = (const float*)d_in[0];
    const float* logits = (const float*)d_in[1];
    const float* mu     = (const float*)d_in[2];
    const float* ls     = (const float*)d_in[3];
    float* out = (float*)d_out;
    const int T = in_sizes[0];                 // 500000 = 16 * 31250 (exact)

    const int nchunks = (T + CHUNK_L - 1) / CHUNK_L;
    const int nwaves  = (nchunks + 15) / 16;
    const int blocks  = (nwaves + 3) / 4;
    hmm_filter_kernel<<<blocks, 256, 0, stream>>>(y, logits, mu, ls, out,
                                                  T, nchunks);
}

// Round 9
// 89.983 us; speedup vs baseline: 1.0953x; 1.0953x over previous
//
#include <hip/hip_runtime.h>

// MFMA-batched overlapped-chunk HMM forward filter + CORRECT LDS-staged
// full-line stores.
// R14: R13 (nt stores) regressed 18.2->27.7us kernel => L2 was merging our
// partial-line stores; effective 3.6TB/s is write-allocate fetch (66MB hidden
// HBM reads; 132MB/6.3TB/s ~= 21us ~= observed). Fills avoid it by writing
// full lines per instruction (FETCH~0). R11 tried full-line flush but its
// staging layout col*64 had col*64%32==0 for ALL cols -> 16-way LDS bank
// conflict on every ds_write (5.7x, m136) + 0.96 waves/SIMD -> unfair test.
// This round: R12 base (CHUNK_L=16, 1.9 w/SIMD), wave-private LDS staging
// with stride-68 rows (2-way banks = free), flush 4-step tiles as 4x256B
// contiguous segments per instr (full-line no-allocate), ft staged and
// flushed 1KB-contiguous per wave. Arithmetic identical -> absmax same.
#define CHUNK_L 16
#define WARMUP_W 16

typedef _Float16 h16;
typedef _Float16 h16x4 __attribute__((ext_vector_type(4)));
typedef float f32x4 __attribute__((ext_vector_type(4)));

static __device__ __forceinline__ f32x4 mfma16(h16x4 a, h16x4 b, f32x4 c) {
#if __has_builtin(__builtin_amdgcn_mfma_f32_16x16x16f16)
    return __builtin_amdgcn_mfma_f32_16x16x16f16(a, b, c, 0, 0, 0);
#else
    f32x4 d;
    asm volatile("v_mfma_f32_16x16x16_f16 %0, %1, %2, %3\n\ts_nop 7\n\ts_nop 7"
                 : "=v"(d) : "v"(a), "v"(b), "v"(c));
    return d;
#endif
}

__global__ __launch_bounds__(256, 4) void hmm_filter_kernel(
    const float* __restrict__ y,
    const float* __restrict__ logits,
    const float* __restrict__ mu,
    const float* __restrict__ log_sigma,
    float* __restrict__ out,
    int T, int nchunks)
{
    __shared__ float Plds[256];
    __shared__ float Ba[256];
    __shared__ float Bb[256];
    // wave-private staging: stride 68 floats/chunk (68%32=4 -> 2-way banks)
    __shared__ float SDu[4][16 * 68];   // ut   [wave][chunk][t0..3][state]+pad
    __shared__ float SDn[4][16 * 68];   // u_norm
    __shared__ float SDf[4][16 * 20];   // ft   [wave][chunk][t0..15]+pad

    const int tid = (int)threadIdx.x;
    const int j   = tid & 15;     // column (preamble)
    const int gr  = tid >> 4;     // row (preamble)

    // ---- P = softmax(logits, axis=-1) ----
    float l = logits[tid];
    float m = l;
    #pragma unroll
    for (int s = 1; s < 16; s <<= 1) m = fmaxf(m, __shfl_xor(m, s, 16));
    float e = __expf(l - m);
    float rs = e;
    #pragma unroll
    for (int s = 1; s < 16; s <<= 1) rs += __shfl_xor(rs, s, 16);
    float Pv = e / rs;
    Plds[tid] = Pv;
    Ba[tid]   = Pv;
    __syncthreads();

    // ---- stationary pi: P^(2^10) via renormalized squaring (cold) ----
    float* cur = Ba;
    float* nxt = Bb;
    for (int itq = 0; itq < 10; ++itq) {
        float acc = 0.f;
        #pragma unroll
        for (int k = 0; k < 16; ++k)
            acc += cur[gr * 16 + k] * cur[k * 16 + j];
        float rsum = acc;
        #pragma unroll
        for (int s = 1; s < 16; s <<= 1) rsum += __shfl_xor(rsum, s, 16);
        nxt[tid] = acc / rsum;
        __syncthreads();
        float* tmp = cur; cur = nxt; nxt = tmp;
    }
    // no barriers below this point (early return is safe)

    // ---- lane / wave geometry ----
    const int lane = tid & 63;
    const int col  = lane & 15;          // chunk column  (n)
    const int i0   = (lane >> 4) << 2;   // first of this lane's 4 states
    const int w    = tid >> 6;           // wave id in block
    const int wv   = ((int)blockIdx.x << 2) + w;
    const int cbase = wv << 4;

    // A = P^T fragments, hi/lo f16 split.
    h16x4 Ahi, Alo;
    #pragma unroll
    for (int ee = 0; ee < 4; ++ee) {
        float a = Plds[(i0 + ee) * 16 + col];
        h16 hi = (h16)a;
        Ahi[ee] = hi;
        Alo[ee] = (h16)(a - (float)hi);
    }

    // initial p~ = pi
    h16x4 bhi, blo;
    #pragma unroll
    for (int ee = 0; ee < 4; ++ee) {
        float pv = cur[i0 + ee];
        h16 hi = (h16)pv;
        bhi[ee] = hi;
        blo[ee] = (h16)(pv - (float)hi);
    }

    // emission constants for this lane's 4 states
    float isv[4], nmv[4], lcv[4];
    #pragma unroll
    for (int ee = 0; ee < 4; ++ee) {
        int st = i0 + ee;
        float is = __expf(-log_sigma[st]);
        isv[ee] = is;
        nmv[ee] = -mu[st] * is;
        lcv[ee] = __log2f(0.3989422804014327f * is);
    }
    const float K2 = -0.7213475204444817f;   // -0.5*log2(e)

    if (cbase >= nchunks) return;

    const int chunk = cbase + col;
    const bool isC0 = (chunk == 0);          // warm with g==1 (pi stationary)
    const int Tm4 = T - 4;
    const int TN  = T << 4;

    int tb = chunk * CHUNK_L - WARMUP_W;     // t of current y 4-block

    auto yld = [&](int t) -> float4 {
        int tc = t < 0 ? 0 : (t > Tm4 ? Tm4 : t);
        return *(const float4*)(y + tc);
    };

    float4 c4 = yld(tb);
    float4 n1 = yld(tb + 4);

    float r1 = 1.0f;   // rcp(rowsum of previous step) = 1/c_{t-1}

// One filter step. Chain: 3 MFMA -> *eg -> f16 split. rowsum/rcp, staging
// hang off the chain. DOST: stage ut/un tile rows into wave-private LDS
// (2-way banks, free); flushed as full-line global stores per 4-block.
#define FSTEP(YT, WARM, DOST, TS, FDST)  do {                             \
    f32x4 D = {0.f, 0.f, 0.f, 0.f};                                       \
    D = mfma16(Ahi, bhi, D);                                              \
    D = mfma16(Alo, bhi, D);                                              \
    D = mfma16(Ahi, blo, D);                                              \
    f32x4 eg;                                                             \
    _Pragma("unroll")                                                     \
    for (int ee = 0; ee < 4; ++ee) {                                      \
        float z  = fmaf((YT), isv[ee], nmv[ee]);                          \
        float gg = __builtin_amdgcn_exp2f(fmaf(z * z, K2, lcv[ee]));      \
        if (WARM) gg = isC0 ? 1.0f : gg;                                  \
        eg[ee] = gg * r1;                                                 \
    }                                                                     \
    f32x4 pg = D * eg;                                                    \
    float sv = (pg.x + pg.y) + (pg.z + pg.w);                             \
    sv += __shfl_xor(sv, 16);                                             \
    sv += __shfl_xor(sv, 32);                                             \
    float rv = __builtin_amdgcn_rcpf(sv);                                 \
    if (DOST) {                                                           \
        *(f32x4*)(&SDu[w][col * 68 + (TS) * 16 + i0]) = D * r1;           \
        *(f32x4*)(&SDn[w][col * 68 + (TS) * 16 + i0]) = pg * rv;          \
        FDST = sv;                                                        \
    }                                                                     \
    _Pragma("unroll")                                                     \
    for (int ee = 0; ee < 4; ++ee) {                                      \
        h16 hh = (h16)pg[ee];                                             \
        bhi[ee] = hh;                                                     \
        blo[ee] = (h16)(pg[ee] - (float)hh);                              \
    }                                                                     \
    r1 = rv;                                                              \
} while (0)

    // ---- warm-up: 16 steps, no stores ----
    float fdummy;
    #pragma unroll 1
    for (int b = 0; b < WARMUP_W / 4; ++b) {
        float4 nn = yld(tb + 8);
        FSTEP(c4.x, true, false, 0, fdummy);
        FSTEP(c4.y, true, false, 0, fdummy);
        FSTEP(c4.z, true, false, 0, fdummy);
        FSTEP(c4.w, true, false, 0, fdummy);
        c4 = n1; n1 = nn; tb += 4;
    }
    (void)fdummy;

    // ---- main: CHUNK_L steps; stage to LDS, flush full lines ----
    f32x4 f4;

    #pragma unroll 1
    for (int b = 0; b < CHUNK_L / 4; ++b) {
        float4 nn = yld(tb + 8);
        FSTEP(c4.x, false, true, 0, f4.x);
        FSTEP(c4.y, false, true, 1, f4.y);
        FSTEP(c4.z, false, true, 2, f4.z);
        FSTEP(c4.w, false, true, 3, f4.w);
        if (lane < 16)
            *(f32x4*)(&SDf[w][col * 20 + b * 4]) = f4;

        // flush: instr i writes 4 chunks x 256B contiguous (full 128B lines)
        #pragma unroll
        for (int i = 0; i < 4; ++i) {
            const int cl  = i * 4 + (lane >> 4);
            const int off = lane & 15;
            f32x4 vu = *(f32x4*)(&SDu[w][cl * 68 + off * 4]);
            f32x4 vn = *(f32x4*)(&SDn[w][cl * 68 + off * 4]);
            const int cc = cbase + cl;
            if (cc < nchunks) {
                float* dst = out + (size_t)cc * 256 + b * 64 + off * 4;
                *(f32x4*)dst        = vu;
                *(f32x4*)(dst + TN) = vn;
            }
        }
        c4 = n1; n1 = nn; tb += 4;
    }

    // ---- ft flush: 1KB contiguous per wave (full lines) ----
    {
        const int cc = cbase + (lane >> 2);
        if (cc < nchunks) {
            f32x4 fv = *(f32x4*)(&SDf[w][(lane >> 2) * 20 + (lane & 3) * 4]);
            float* dst = out + 2 * (size_t)TN + (size_t)cbase * 16 + lane * 4;
            *(f32x4*)dst = fv;
        }
    }
#undef FSTEP
}

extern "C" void kernel_launch(void* const* d_in, const int* in_sizes, int n_in,
                              void* d_out, int out_size, void* d_ws, size_t ws_size,
                              hipStream_t stream) {
    const float* y      = (const float*)d_in[0];
    const float* logits = (const float*)d_in[1];
    const float* mu     = (const float*)d_in[2];
    const float* ls     = (const float*)d_in[3];
    float* out = (float*)d_out;
    const int T = in_sizes[0];                 // 500000 = 16 * 31250 (exact)

    const int nchunks = (T + CHUNK_L - 1) / CHUNK_L;
    const int nwaves  = (nchunks + 15) / 16;
    const int blocks  = (nwaves + 3) / 4;
    hmm_filter_kernel<<<blocks, 256, 0, stream>>>(y, logits, mu, ls, out,
                                                  T, nchunks);
}